// Round 6
// baseline (15.780 us; speedup 1.0000x reference)
//
#include <hip/hip_runtime.h>

// EulerMisorientation3D — two-kernel (partials + 1-wave finalize).
//
// Algebra (absmax 0.0 since R2): only diagonals of g_hat and inv(g) matter;
// for a rotation diag(inv(g)) = diag(g). Product-to-sum:
//   c1*c2 = 0.5*(cos(p1+p2)+cos(p1-p2)), s1*s2 = 0.5*(cos(p1-p2)-cos(p1+p2))
// v_cos_f32 takes REVOLUTIONS -> args are x0±x2 and 0.5*x1, no range
// reduction. 6 cos + 1 acos per voxel.
//
// Structure lessons:
//  R2: per-block release fence => per-block L2 writeback => 118us. Never.
//  R4: relaxed agent-scope atomics + ticket => 30us. Never.
//  R3: two plain kernels, serialized loads (VGPR=16) => 18.2us.
//  R5: 12 explicit in-flight float4 loads, 16 waves/CU => 15.7us.
//  R6: same 12-load MLP but force VGPR<=64 via __launch_bounds__(256,8)
//      -> 32 waves/CU -> 384 outstanding loads/CU (2x R5's 192).

#define NTHR 256
#define NBLK 1024   // 1024 blocks * 256 thr * 2 quads * 4 vox = 2,097,152

__device__ __forceinline__ float voxel_mis(float u0, float u1, float u2,
                                           float v0, float v1, float v2) {
    const float A  = __builtin_amdgcn_cosf(u0 + u2);
    const float Bc = __builtin_amdgcn_cosf(u0 - u2);
    const float cP = __builtin_amdgcn_cosf(0.5f * u1);
    const float p  = 0.5f * (A + Bc);      // c1*c2
    const float q  = 0.5f * (Bc - A);      // s1*s2
    const float g00 = fmaf(-q, cP, p);
    const float g11 = fmaf(p, cP, -q);

    const float Ah  = __builtin_amdgcn_cosf(v0 + v2);
    const float Bh  = __builtin_amdgcn_cosf(v0 - v2);
    const float cPh = __builtin_amdgcn_cosf(0.5f * v1);
    const float ph  = 0.5f * (Ah + Bh);
    const float qh  = 0.5f * (Bh - Ah);
    const float h00 = fmaf(-qh, cPh, ph);
    const float h11 = fmaf(ph, cPh, -qh);

    const float tr = fmaf(h00, g00, fmaf(h11, g11, cPh * cP));
    float arg = 0.5f * (tr - 1.0f);
    arg = fminf(1.0f, fmaxf(-1.0f, arg));
    const float m = acosf(arg);
    return m * m;
}

__global__ __launch_bounds__(NTHR, 8)   // 8 waves/EU -> VGPR budget 64 -> 32 waves/CU
void euler_mis_partial(const float* __restrict__ x, const float* __restrict__ xh,
                       float* __restrict__ partials, int nvox) {
    const int tid = threadIdx.x;
    const int g0 = blockIdx.x * (NTHR * 2) + tid;   // first float4 index
    const int g1 = g0 + NTHR;                       // second float4 index

    const float4* p0 = reinterpret_cast<const float4*>(x);
    const float4* p1 = reinterpret_cast<const float4*>(x + (size_t)nvox);
    const float4* p2 = reinterpret_cast<const float4*>(x + 2 * (size_t)nvox);
    const float4* q0 = reinterpret_cast<const float4*>(xh);
    const float4* q1 = reinterpret_cast<const float4*>(xh + (size_t)nvox);
    const float4* q2 = reinterpret_cast<const float4*>(xh + 2 * (size_t)nvox);

    // Issue ALL 12 independent loads before any compute (MLP).
    const float4 a0 = p0[g0], a1 = p1[g0], a2 = p2[g0];
    const float4 b0 = q0[g0], b1 = q1[g0], b2 = q2[g0];
    const float4 c0 = p0[g1], c1 = p1[g1], c2 = p2[g1];
    const float4 d0 = q0[g1], d1 = q1[g1], d2 = q2[g1];

    // Consume batch 0 first so its 24 regs free up for batch-1 temps.
    float acc = 0.f;
    acc += voxel_mis(a0.x, a1.x, a2.x, b0.x, b1.x, b2.x);
    acc += voxel_mis(a0.y, a1.y, a2.y, b0.y, b1.y, b2.y);
    acc += voxel_mis(a0.z, a1.z, a2.z, b0.z, b1.z, b2.z);
    acc += voxel_mis(a0.w, a1.w, a2.w, b0.w, b1.w, b2.w);
    acc += voxel_mis(c0.x, c1.x, c2.x, d0.x, d1.x, d2.x);
    acc += voxel_mis(c0.y, c1.y, c2.y, d0.y, d1.y, d2.y);
    acc += voxel_mis(c0.z, c1.z, c2.z, d0.z, d1.z, d2.z);
    acc += voxel_mis(c0.w, c1.w, c2.w, d0.w, d1.w, d2.w);

    // block reduce: wave64 butterfly + LDS
    #pragma unroll
    for (int off = 32; off > 0; off >>= 1) acc += __shfl_down(acc, off, 64);
    __shared__ float lds[4];
    if ((tid & 63) == 0) lds[tid >> 6] = acc;
    __syncthreads();
    if (tid == 0) partials[blockIdx.x] = lds[0] + lds[1] + lds[2] + lds[3];
}

__global__ __launch_bounds__(64)
void euler_mis_finalize(const float* __restrict__ partials,
                        float* __restrict__ out, float inv_n) {
    // One wave reads NBLK=1024 partials as 256 float4s: 4 per lane. No LDS.
    const int lane = threadIdx.x;
    const float4* p = reinterpret_cast<const float4*>(partials);
    float s = 0.f;
    #pragma unroll
    for (int r = 0; r < 4; ++r) {
        const float4 v = p[lane + 64 * r];
        s += (v.x + v.y) + (v.z + v.w);
    }
    #pragma unroll
    for (int off = 32; off > 0; off >>= 1) s += __shfl_down(s, off, 64);
    if (lane == 0) out[0] = s * inv_n;
}

extern "C" void kernel_launch(void* const* d_in, const int* in_sizes, int n_in,
                              void* d_out, int out_size, void* d_ws, size_t ws_size,
                              hipStream_t stream) {
    const float* x  = (const float*)d_in[0];
    const float* xh = (const float*)d_in[1];
    float* out = (float*)d_out;
    float* partials = (float*)d_ws;

    const int nvox = in_sizes[0] / 3;   // 128^3 = 2,097,152

    euler_mis_partial<<<NBLK, NTHR, 0, stream>>>(x, xh, partials, nvox);
    euler_mis_finalize<<<1, 64, 0, stream>>>(partials, out, 1.0f / (float)nvox);
}

// Round 7
// 15.750 us; speedup vs baseline: 1.0019x; 1.0019x over previous
//
#include <hip/hip_runtime.h>

// EulerMisorientation3D — two-kernel (per-wave partials + small finalize).
//
// Algebra: only diagonals of g_hat and inv(g) matter; for a rotation
// diag(inv(g)) = diag(g). Product-to-sum gives diagonals from 3 hw cos per
// matrix, in REVOLUTIONS (args x0±x2, 0.5*x1) — no range reduction.
// Work with DOUBLED diagonals (P=2c1c2, Q=2s1s2) and fold one 0.25 into the
// trace to save the per-matrix 0.5 muls.
//
// acos: branchless minimax (AS 4.4.45), |err| <= ~7e-5 rad; mean-error ~1e-5
// vs 4.4e-2 threshold. Replaces ~30-inst branchy libm acosf with 8 VALU + 1
// v_sqrt. Kernel1 VALU ~30 inst/voxel -> hidden under the ~8us HBM stream.
//
// Structure lessons:
//  R2: per-block release fence => per-block L2 writeback => 118us. Never.
//  R4: relaxed agent-scope atomics + ticket => 30us. Never.
//  R3: two plain kernels, serialized loads => 18.2us.
//  R5: 12 explicit in-flight float4 loads => 15.7us.
//  R6: VGPR/occupancy squeeze => neutral (not occupancy-bound).
//  R7: minimax acos + doubled-diag algebra + per-wave partials (no
//      __syncthreads in kernel1).

#define NTHR 256
#define NBLK 1024   // 1024 blocks * 256 thr * 2 quads * 4 vox = 2,097,152
#define NPART (NBLK * 4)   // one partial per wave

__device__ __forceinline__ float voxel_mis(float u0, float u1, float u2,
                                           float v0, float v1, float v2) {
    // g diag, doubled: G00 = 2*g00, G11 = 2*g11
    const float A  = __builtin_amdgcn_cosf(u0 + u2);
    const float B  = __builtin_amdgcn_cosf(u0 - u2);
    const float cP = __builtin_amdgcn_cosf(0.5f * u1);
    const float P  = A + B;                 // 2*c1c2
    const float Q  = B - A;                 // 2*s1s2
    const float G00 = fmaf(-Q, cP, P);
    const float G11 = fmaf(P, cP, -Q);

    const float Ah  = __builtin_amdgcn_cosf(v0 + v2);
    const float Bh  = __builtin_amdgcn_cosf(v0 - v2);
    const float cPh = __builtin_amdgcn_cosf(0.5f * v1);
    const float Ph  = Ah + Bh;
    const float Qh  = Bh - Ah;
    const float H00 = fmaf(-Qh, cPh, Ph);
    const float H11 = fmaf(Ph, cPh, -Qh);

    // tr = 0.25*(G00*H00 + G11*H11) + cP*cPh
    const float t  = fmaf(G00, H00, G11 * H11);
    const float tr = fmaf(0.25f, t, cP * cPh);

    float z = fmaf(0.5f, tr, -0.5f);
    z = fminf(1.0f, fmaxf(-1.0f, z));

    // acos(x) ~= sqrt(1-x) * (a0 + a1 x + a2 x^2 + a3 x^3), x in [0,1];
    // x<0 via acos(x) = pi - acos(-x). Branchless.
    const float ax = fabsf(z);
    const float s  = __builtin_amdgcn_sqrtf(1.0f - ax);
    float pp = fmaf(ax, -0.0187293f, 0.0742610f);
    pp = fmaf(ax, pp, -0.2121144f);
    pp = fmaf(ax, pp, 1.5707288f);
    const float r = s * pp;
    const float m = (z >= 0.0f) ? r : (3.14159265358979f - r);
    return m * m;
}

__global__ __launch_bounds__(NTHR)
void euler_mis_partial(const float* __restrict__ x, const float* __restrict__ xh,
                       float* __restrict__ partials, int nvox) {
    const int tid = threadIdx.x;
    const int g0 = blockIdx.x * (NTHR * 2) + tid;   // first float4 index
    const int g1 = g0 + NTHR;                       // second float4 index

    const float4* p0 = reinterpret_cast<const float4*>(x);
    const float4* p1 = reinterpret_cast<const float4*>(x + (size_t)nvox);
    const float4* p2 = reinterpret_cast<const float4*>(x + 2 * (size_t)nvox);
    const float4* q0 = reinterpret_cast<const float4*>(xh);
    const float4* q1 = reinterpret_cast<const float4*>(xh + (size_t)nvox);
    const float4* q2 = reinterpret_cast<const float4*>(xh + 2 * (size_t)nvox);

    // Issue ALL 12 independent loads before any compute (MLP).
    const float4 a0 = p0[g0], a1 = p1[g0], a2 = p2[g0];
    const float4 b0 = q0[g0], b1 = q1[g0], b2 = q2[g0];
    const float4 c0 = p0[g1], c1 = p1[g1], c2 = p2[g1];
    const float4 d0 = q0[g1], d1 = q1[g1], d2 = q2[g1];

    float acc = 0.f;
    acc += voxel_mis(a0.x, a1.x, a2.x, b0.x, b1.x, b2.x);
    acc += voxel_mis(a0.y, a1.y, a2.y, b0.y, b1.y, b2.y);
    acc += voxel_mis(a0.z, a1.z, a2.z, b0.z, b1.z, b2.z);
    acc += voxel_mis(a0.w, a1.w, a2.w, b0.w, b1.w, b2.w);
    acc += voxel_mis(c0.x, c1.x, c2.x, d0.x, d1.x, d2.x);
    acc += voxel_mis(c0.y, c1.y, c2.y, d0.y, d1.y, d2.y);
    acc += voxel_mis(c0.z, c1.z, c2.z, d0.z, d1.z, d2.z);
    acc += voxel_mis(c0.w, c1.w, c2.w, d0.w, d1.w, d2.w);

    // wave64 butterfly; one partial per wave — NO __syncthreads, NO LDS.
    #pragma unroll
    for (int off = 32; off > 0; off >>= 1) acc += __shfl_down(acc, off, 64);
    if ((tid & 63) == 0) partials[blockIdx.x * 4 + (tid >> 6)] = acc;
}

__global__ __launch_bounds__(NTHR)
void euler_mis_finalize(const float* __restrict__ partials,
                        float* __restrict__ out, float inv_n) {
    // 4096 partials = 1024 float4; 256 threads x 4 float4 each.
    const int tid = threadIdx.x;
    const float4* p = reinterpret_cast<const float4*>(partials);
    float s = 0.f;
    #pragma unroll
    for (int r = 0; r < 4; ++r) {
        const float4 v = p[tid + NTHR * r];
        s += (v.x + v.y) + (v.z + v.w);
    }
    #pragma unroll
    for (int off = 32; off > 0; off >>= 1) s += __shfl_down(s, off, 64);
    __shared__ float lds[4];
    if ((tid & 63) == 0) lds[tid >> 6] = s;
    __syncthreads();
    if (tid == 0) out[0] = (lds[0] + lds[1] + lds[2] + lds[3]) * inv_n;
}

extern "C" void kernel_launch(void* const* d_in, const int* in_sizes, int n_in,
                              void* d_out, int out_size, void* d_ws, size_t ws_size,
                              hipStream_t stream) {
    const float* x  = (const float*)d_in[0];
    const float* xh = (const float*)d_in[1];
    float* out = (float*)d_out;
    float* partials = (float*)d_ws;

    const int nvox = in_sizes[0] / 3;   // 128^3 = 2,097,152

    euler_mis_partial<<<NBLK, NTHR, 0, stream>>>(x, xh, partials, nvox);
    euler_mis_finalize<<<1, NTHR, 0, stream>>>(partials, out, 1.0f / (float)nvox);
}

// Round 8
// 15.478 us; speedup vs baseline: 1.0195x; 1.0176x over previous
//
#include <hip/hip_runtime.h>

// EulerMisorientation3D — two-kernel (per-wave partials + 1-wave finalize).
//
// Algebra (absmax 0.0 across R2-R7): only diagonals of g_hat and inv(g)
// matter; for a rotation diag(inv(g)) = diag(g). Product-to-sum:
//   2*c1c2 = cos(p1+p2)+cos(p1-p2), 2*s1s2 = cos(p1-p2)-cos(p1+p2)
// hw cos takes REVOLUTIONS -> args x0±x2, 0.5*x1; no range reduction.
// Branchless minimax acos (AS 4.4.45), error ~7e-5 rad << 4.4e-2 threshold.
//
// Structure lessons:
//  R2: per-block release fence => L2 writeback storm => 118us. Never.
//  R4: relaxed agent-scope atomics + ticket => 30us. Never.
//  R3: two kernels, serialized loads => 18.2us.
//  R5: 12 in-flight float4 loads/thread => 15.7us.
//  R6: occupancy 2x (VGPR<=64) => neutral. Not occupancy-bound.
//  R7: VALU halved (minimax acos) => neutral. Not VALU-bound.
//  R8: per-wave MLP 12 -> 24 loads (VPT=4, 512 blocks); 1-wave finalize.
//      Harness re-poisons 268MB ws between replays -> inputs half-evicted
//      from L3; normal (caching) loads are correct, nt would hurt.

#define NTHR 256
#define NBLK 512    // 512 blocks * 256 thr * 4 quads * 4 vox = 2,097,152
#define NPART (NBLK * 4)   // one partial per wave = 2048

__device__ __forceinline__ float voxel_mis(float u0, float u1, float u2,
                                           float v0, float v1, float v2) {
    const float A  = __builtin_amdgcn_cosf(u0 + u2);
    const float B  = __builtin_amdgcn_cosf(u0 - u2);
    const float cP = __builtin_amdgcn_cosf(0.5f * u1);
    const float P  = A + B;                 // 2*c1c2
    const float Q  = B - A;                 // 2*s1s2
    const float G00 = fmaf(-Q, cP, P);
    const float G11 = fmaf(P, cP, -Q);

    const float Ah  = __builtin_amdgcn_cosf(v0 + v2);
    const float Bh  = __builtin_amdgcn_cosf(v0 - v2);
    const float cPh = __builtin_amdgcn_cosf(0.5f * v1);
    const float Ph  = Ah + Bh;
    const float Qh  = Bh - Ah;
    const float H00 = fmaf(-Qh, cPh, Ph);
    const float H11 = fmaf(Ph, cPh, -Qh);

    const float t  = fmaf(G00, H00, G11 * H11);
    const float tr = fmaf(0.25f, t, cP * cPh);

    float z = fmaf(0.5f, tr, -0.5f);
    z = fminf(1.0f, fmaxf(-1.0f, z));

    const float ax = fabsf(z);
    const float s  = __builtin_amdgcn_sqrtf(1.0f - ax);
    float pp = fmaf(ax, -0.0187293f, 0.0742610f);
    pp = fmaf(ax, pp, -0.2121144f);
    pp = fmaf(ax, pp, 1.5707288f);
    const float r = s * pp;
    const float m = (z >= 0.0f) ? r : (3.14159265358979f - r);
    return m * m;
}

__device__ __forceinline__ float quad_mis(const float4& a0, const float4& a1,
                                          const float4& a2, const float4& b0,
                                          const float4& b1, const float4& b2) {
    float acc;
    acc  = voxel_mis(a0.x, a1.x, a2.x, b0.x, b1.x, b2.x);
    acc += voxel_mis(a0.y, a1.y, a2.y, b0.y, b1.y, b2.y);
    acc += voxel_mis(a0.z, a1.z, a2.z, b0.z, b1.z, b2.z);
    acc += voxel_mis(a0.w, a1.w, a2.w, b0.w, b1.w, b2.w);
    return acc;
}

__global__ __launch_bounds__(NTHR)
void euler_mis_partial(const float* __restrict__ x, const float* __restrict__ xh,
                       float* __restrict__ partials, int nvox) {
    const int tid = threadIdx.x;
    const int g0 = blockIdx.x * (NTHR * 4) + tid;

    const float4* p0 = reinterpret_cast<const float4*>(x);
    const float4* p1 = reinterpret_cast<const float4*>(x + (size_t)nvox);
    const float4* p2 = reinterpret_cast<const float4*>(x + 2 * (size_t)nvox);
    const float4* q0 = reinterpret_cast<const float4*>(xh);
    const float4* q1 = reinterpret_cast<const float4*>(xh + (size_t)nvox);
    const float4* q2 = reinterpret_cast<const float4*>(xh + 2 * (size_t)nvox);

    // Issue ALL 24 independent float4 loads before any compute (deep MLP).
    const float4 a0 = p0[g0],          a1 = p1[g0],          a2 = p2[g0];
    const float4 b0 = q0[g0],          b1 = q1[g0],          b2 = q2[g0];
    const float4 c0 = p0[g0 + NTHR],   c1 = p1[g0 + NTHR],   c2 = p2[g0 + NTHR];
    const float4 d0 = q0[g0 + NTHR],   d1 = q1[g0 + NTHR],   d2 = q2[g0 + NTHR];
    const float4 e0 = p0[g0 + 2*NTHR], e1 = p1[g0 + 2*NTHR], e2 = p2[g0 + 2*NTHR];
    const float4 f0 = q0[g0 + 2*NTHR], f1 = q1[g0 + 2*NTHR], f2 = q2[g0 + 2*NTHR];
    const float4 h0 = p0[g0 + 3*NTHR], h1 = p1[g0 + 3*NTHR], h2 = p2[g0 + 3*NTHR];
    const float4 k0 = q0[g0 + 3*NTHR], k1 = q1[g0 + 3*NTHR], k2 = q2[g0 + 3*NTHR];

    float acc = quad_mis(a0, a1, a2, b0, b1, b2);
    acc += quad_mis(c0, c1, c2, d0, d1, d2);
    acc += quad_mis(e0, e1, e2, f0, f1, f2);
    acc += quad_mis(h0, h1, h2, k0, k1, k2);

    // wave64 butterfly; one partial per wave — no __syncthreads, no LDS.
    #pragma unroll
    for (int off = 32; off > 0; off >>= 1) acc += __shfl_down(acc, off, 64);
    if ((tid & 63) == 0) partials[blockIdx.x * 4 + (tid >> 6)] = acc;
}

__global__ __launch_bounds__(64)
void euler_mis_finalize(const float* __restrict__ partials,
                        float* __restrict__ out, float inv_n) {
    // 2048 partials = 512 float4; one wave, 8 float4 per lane. No LDS.
    const int lane = threadIdx.x;
    const float4* p = reinterpret_cast<const float4*>(partials);
    float s = 0.f;
    #pragma unroll
    for (int r = 0; r < 8; ++r) {
        const float4 v = p[lane + 64 * r];
        s += (v.x + v.y) + (v.z + v.w);
    }
    #pragma unroll
    for (int off = 32; off > 0; off >>= 1) s += __shfl_down(s, off, 64);
    if (lane == 0) out[0] = s * inv_n;
}

extern "C" void kernel_launch(void* const* d_in, const int* in_sizes, int n_in,
                              void* d_out, int out_size, void* d_ws, size_t ws_size,
                              hipStream_t stream) {
    const float* x  = (const float*)d_in[0];
    const float* xh = (const float*)d_in[1];
    float* out = (float*)d_out;
    float* partials = (float*)d_ws;

    const int nvox = in_sizes[0] / 3;   // 128^3 = 2,097,152

    euler_mis_partial<<<NBLK, NTHR, 0, stream>>>(x, xh, partials, nvox);
    euler_mis_finalize<<<1, 64, 0, stream>>>(partials, out, 1.0f / (float)nvox);
}